// Round 1
// baseline (2915.723 us; speedup 1.0000x reference)
//
#include <hip/hip_runtime.h>
#include <math.h>

// Problem constants (from reference): N=2, K=20 -> 40 images, C=64, H=W=16.
#define NIMG 40
#define NC 64
#define HW 256
#define W16 16

// ---------------------------------------------------------------------------
// Generic 3x3 SAME conv, direct, fp32.
//   in:  (NIMG, CIN_data, 16, 16)  (CIN_data = CIN-1 if TCHAN else CIN)
//   w:   (64, WSTRIDE, 3, 3), we use channels [WOFF, WOFF+CIN)
//   out: (NIMG, 64, 16, 16)
// Block: 512 threads = 2 sub-groups x 256 pixels; each thread: 8 oc accums.
// Grid: (NIMG, 4) -> blockIdx.y selects 16-oc group.
// ---------------------------------------------------------------------------
template<int CIN, int WSTRIDE, int WOFF, bool RELU, bool TCHAN>
__global__ __launch_bounds__(512)
void conv3x3_k(const float* __restrict__ in, const float* __restrict__ w,
               const float* __restrict__ bias, float* __restrict__ out,
               const float* __restrict__ tptr)
{
    __shared__ float lds[CIN * HW];
    const int img = blockIdx.x;
    const int tid = threadIdx.x;

    // stage input image into LDS
    if (TCHAN) {
        const float tval = tptr[0];
        for (int idx = tid; idx < CIN * HW; idx += 512) {
            int c = idx >> 8;
            lds[idx] = (c == 0) ? tval : in[(size_t)img * (CIN - 1) * HW + idx - HW];
        }
    } else {
        const float4* in4 = (const float4*)(in + (size_t)img * CIN * HW);
        float4* lds4 = (float4*)lds;
        for (int idx = tid; idx < CIN * HW / 4; idx += 512)
            lds4[idx] = in4[idx];
    }
    __syncthreads();

    const int px  = tid & 255;
    const int sub = tid >> 8;
    const int oc0 = blockIdx.y * 16 + sub * 8;
    const int y = px >> 4, x = px & 15;

    float acc[8];
#pragma unroll
    for (int o = 0; o < 8; ++o) acc[o] = bias ? bias[oc0 + o] : 0.f;

    for (int ci = 0; ci < CIN; ++ci) {
        const float* wp = w + ((size_t)oc0 * WSTRIDE + WOFF + ci) * 9;
        const float* lrow = lds + ci * HW;
#pragma unroll
        for (int ky = 0; ky < 3; ++ky) {
            const int yy = y + ky - 1;
            if (yy < 0 || yy > 15) continue;
#pragma unroll
            for (int kx = 0; kx < 3; ++kx) {
                const int xx = x + kx - 1;
                if (xx < 0 || xx > 15) continue;
                const float v = lrow[yy * W16 + xx];
#pragma unroll
                for (int o = 0; o < 8; ++o)
                    acc[o] = fmaf(v, wp[o * WSTRIDE * 9 + ky * 3 + kx], acc[o]);
            }
        }
    }
#pragma unroll
    for (int o = 0; o < 8; ++o) {
        float v = RELU ? fmaxf(acc[o], 0.f) : acc[o];
        out[((size_t)img * NC + oc0 + o) * HW + px] = v;
    }
}

// ---------------------------------------------------------------------------
// Pair message kernel.
// For output node b (image nb = n*20+b), sum over source a of
//   (conv(relu(A[b]+B[a]), w_b2)+b_b2) * sigmoid(conv(relu(Ag[b]+Bg[a]), w_bg2)+b_bg2)
// b_b1/b_bg1 are folded into A/Ag as conv bias.
// Grid: (40, 4 oc-groups of 16, 5 a-splits of 4). Block 512.
// ---------------------------------------------------------------------------
__device__ __forceinline__
void conv_accum64(const float* __restrict__ lds, const float* __restrict__ w,
                  int oc0, int y, int x, float acc[8])
{
    for (int ci = 0; ci < NC; ++ci) {
        const float* wp = w + ((size_t)oc0 * NC + ci) * 9;
        const float* lrow = lds + ci * HW;
#pragma unroll
        for (int ky = 0; ky < 3; ++ky) {
            const int yy = y + ky - 1;
            if (yy < 0 || yy > 15) continue;
#pragma unroll
            for (int kx = 0; kx < 3; ++kx) {
                const int xx = x + kx - 1;
                if (xx < 0 || xx > 15) continue;
                const float v = lrow[yy * W16 + xx];
#pragma unroll
                for (int o = 0; o < 8; ++o)
                    acc[o] = fmaf(v, wp[o * NC * 9 + ky * 3 + kx], acc[o]);
            }
        }
    }
}

__global__ __launch_bounds__(512)
void pair_msg_k(const float* __restrict__ A, const float* __restrict__ B,
                const float* __restrict__ Ag, const float* __restrict__ Bg,
                const float* __restrict__ w2, const float* __restrict__ b2,
                const float* __restrict__ wg2, const float* __restrict__ bg2,
                float* __restrict__ accum)
{
    __shared__ float lds[NC * HW];
    const int nb = blockIdx.x;      // n*20 + b  (output node image)
    const int n  = nb / 20;
    const int tid = threadIdx.x;
    const int px  = tid & 255;
    const int sub = tid >> 8;
    const int oc0 = blockIdx.y * 16 + sub * 8;
    const int y = px >> 4, x = px & 15;

    const size_t baseA = (size_t)nb * (NC * HW);
    float accout[8];
#pragma unroll
    for (int o = 0; o < 8; ++o) accout[o] = 0.f;

    for (int ia = 0; ia < 4; ++ia) {
        const int a = blockIdx.z * 4 + ia;
        const size_t baseB = ((size_t)(n * 20 + a)) * (NC * HW);

        // stage z = relu(A[b] + B[a])
        {
            const float4* A4 = (const float4*)(A + baseA);
            const float4* B4 = (const float4*)(B + baseB);
            float4* lds4 = (float4*)lds;
            for (int idx = tid; idx < NC * HW / 4; idx += 512) {
                float4 va = A4[idx], vb = B4[idx], v;
                v.x = fmaxf(va.x + vb.x, 0.f);
                v.y = fmaxf(va.y + vb.y, 0.f);
                v.z = fmaxf(va.z + vb.z, 0.f);
                v.w = fmaxf(va.w + vb.w, 0.f);
                lds4[idx] = v;
            }
        }
        __syncthreads();
        float m[8];
#pragma unroll
        for (int o = 0; o < 8; ++o) m[o] = 0.f;
        conv_accum64(lds, w2, oc0, y, x, m);
        __syncthreads();

        // stage zg = relu(Ag[b] + Bg[a])
        {
            const float4* A4 = (const float4*)(Ag + baseA);
            const float4* B4 = (const float4*)(Bg + baseB);
            float4* lds4 = (float4*)lds;
            for (int idx = tid; idx < NC * HW / 4; idx += 512) {
                float4 va = A4[idx], vb = B4[idx], v;
                v.x = fmaxf(va.x + vb.x, 0.f);
                v.y = fmaxf(va.y + vb.y, 0.f);
                v.z = fmaxf(va.z + vb.z, 0.f);
                v.w = fmaxf(va.w + vb.w, 0.f);
                lds4[idx] = v;
            }
        }
        __syncthreads();
        float g[8];
#pragma unroll
        for (int o = 0; o < 8; ++o) g[o] = 0.f;
        conv_accum64(lds, wg2, oc0, y, x, g);
        __syncthreads();

#pragma unroll
        for (int o = 0; o < 8; ++o) {
            float msg  = m[o] + b2[oc0 + o];
            float gate = 1.f / (1.f + expf(-(g[o] + bg2[oc0 + o])));
            accout[o] += msg * gate;
        }
    }
#pragma unroll
    for (int o = 0; o < 8; ++o)
        atomicAdd(&accum[baseA + (size_t)(oc0 + o) * HW + px], accout[o]);
}

// ---------------------------------------------------------------------------
// Final combine: out = u_lin * sigmoid(ug_lin) + accum / 19
// ---------------------------------------------------------------------------
__global__ __launch_bounds__(256)
void final_k(const float* __restrict__ u_lin, const float* __restrict__ ug_lin,
             const float* __restrict__ accum, float* __restrict__ out, int ntot)
{
    int i = blockIdx.x * 256 + threadIdx.x;
    if (i < ntot) {
        float g = 1.f / (1.f + expf(-ug_lin[i]));
        out[i] = u_lin[i] * g + accum[i] * (1.f / 19.f);
    }
}

extern "C" void kernel_launch(void* const* d_in, const int* in_sizes, int n_in,
                              void* d_out, int out_size, void* d_ws, size_t ws_size,
                              hipStream_t stream)
{
    const float* t     = (const float*)d_in[0];
    const float* x     = (const float*)d_in[1];
    const float* w_map = (const float*)d_in[2];
    const float* b_map = (const float*)d_in[3];
    const float* w_u1  = (const float*)d_in[4];
    const float* b_u1  = (const float*)d_in[5];
    const float* w_u2  = (const float*)d_in[6];
    const float* b_u2  = (const float*)d_in[7];
    const float* w_ug1 = (const float*)d_in[8];
    const float* b_ug1 = (const float*)d_in[9];
    const float* w_ug2 = (const float*)d_in[10];
    const float* b_ug2 = (const float*)d_in[11];
    const float* w_b1  = (const float*)d_in[12];
    const float* b_b1  = (const float*)d_in[13];
    const float* w_b2  = (const float*)d_in[14];
    const float* b_b2  = (const float*)d_in[15];
    const float* w_bg1 = (const float*)d_in[16];
    const float* b_bg1 = (const float*)d_in[17];
    const float* w_bg2 = (const float*)d_in[18];
    const float* b_bg2 = (const float*)d_in[19];

    float* out = (float*)d_out;
    float* ws  = (float*)d_ws;
    const size_t S = (size_t)NIMG * NC * HW;   // 655360 elements per tensor

    float* h      = ws + 0 * S;
    float* p1     = ws + 1 * S;
    float* u_lin  = ws + 2 * S;
    float* ug_lin = ws + 3 * S;
    float* A      = ws + 4 * S;
    float* B      = ws + 5 * S;
    float* Ag     = ws + 6 * S;
    float* Bg     = ws + 7 * S;
    float* accum  = ws + 8 * S;

    hipMemsetAsync(accum, 0, S * sizeof(float), stream);

    dim3 blk(512);
    dim3 grd(NIMG, 4);

    // h = conv([t; x], w_map) + b_map
    conv3x3_k<33, 33, 0, false, true><<<grd, blk, 0, stream>>>(x, w_map, b_map, h, t);

    // unary branch
    conv3x3_k<64, 64, 0, true,  false><<<grd, blk, 0, stream>>>(h,  w_u1,  b_u1,  p1,     nullptr);
    conv3x3_k<64, 64, 0, false, false><<<grd, blk, 0, stream>>>(p1, w_u2,  b_u2,  u_lin,  nullptr);
    conv3x3_k<64, 64, 0, true,  false><<<grd, blk, 0, stream>>>(h,  w_ug1, b_ug1, p1,     nullptr);
    conv3x3_k<64, 64, 0, false, false><<<grd, blk, 0, stream>>>(p1, w_ug2, b_ug2, ug_lin, nullptr);

    // binary first-conv halves: A (first 64 in-ch, bias b_b1), B (second 64, no bias)
    conv3x3_k<64, 128, 0,  false, false><<<grd, blk, 0, stream>>>(h, w_b1,  b_b1,  A,  nullptr);
    conv3x3_k<64, 128, 64, false, false><<<grd, blk, 0, stream>>>(h, w_b1,  nullptr, B,  nullptr);
    conv3x3_k<64, 128, 0,  false, false><<<grd, blk, 0, stream>>>(h, w_bg1, b_bg1, Ag, nullptr);
    conv3x3_k<64, 128, 64, false, false><<<grd, blk, 0, stream>>>(h, w_bg1, nullptr, Bg, nullptr);

    // pairwise message accumulation
    pair_msg_k<<<dim3(NIMG, 4, 5), blk, 0, stream>>>(A, B, Ag, Bg,
                                                     w_b2, b_b2, w_bg2, b_bg2, accum);

    // out = u_lin * sigmoid(ug_lin) + accum / (K-1)
    final_k<<<dim3((int)(S / 256)), dim3(256), 0, stream>>>(u_lin, ug_lin, accum, out, (int)S);
}

// Round 2
// 407.903 us; speedup vs baseline: 7.1481x; 7.1481x over previous
//
#include <hip/hip_runtime.h>
#include <math.h>

// N=2, K=20 -> 40 images; C=64 channels; 16x16 images (256 px).
#define NIMG 40
#define PXI  256
#define CH   64
#define SB_ELEM (NIMG * PXI * CH)   // 655360 elems per activation tensor

typedef __bf16 bf16x8 __attribute__((ext_vector_type(8)));
typedef float  f32x4  __attribute__((ext_vector_type(4)));

static __device__ __forceinline__ unsigned short f2bf(float f) {
    unsigned u = __builtin_bit_cast(unsigned, f);
    u += 0x7fffu + ((u >> 16) & 1u);          // RNE
    return (unsigned short)(u >> 16);
}
static __device__ __forceinline__ float bfu2f(unsigned hs) {  // bf16 bits in low 16
    unsigned u = hs << 16;
    return __builtin_bit_cast(float, u);
}

// ---------------------------------------------------------------------------
// Core: one wave computes rows {y0, y0+1} (two 16-px tiles) x all 4 oc-tiles
// of a 3x3 SAME conv, from LDS Z (bf16, swizzled [pix][ci]) and Wt bf16
// [9][64 oc][64 ci]. Accumulates into acc[2][4] (f32x4 each).
// LDS layout: 16B slot index = pix*8 + (g ^ (pix&7)), g = ci/8.
// ---------------------------------------------------------------------------
static __device__ __forceinline__ void conv_tiles2(const uint4* __restrict__ ldsZ,
                                                   const uint4* __restrict__ Wt,
                                                   int y0, int lane, f32x4 acc[2][4])
{
    const int l15 = lane & 15;
    const int l4  = lane >> 4;
#pragma unroll
    for (int khalf = 0; khalf < 2; ++khalf) {
        const int g   = khalf * 4 + l4;          // 16B group of this lane's A/B k-slice
        const int ciu = khalf * 4 + l4;          // uint4 offset within a 64-ci row
#pragma unroll
        for (int kk = 0; kk < 9; ++kk) {
            const int ky = kk / 3 - 1;
            const int kx = kk % 3 - 1;
            bf16x8 bfrag[4];
#pragma unroll
            for (int oct = 0; oct < 4; ++oct) {
                uint4 wv = Wt[(kk * 64 + oct * 16 + l15) * 8 + ciu];
                bfrag[oct] = __builtin_bit_cast(bf16x8, wv);
            }
#pragma unroll
            for (int r = 0; r < 2; ++r) {
                const int yy = y0 + r + ky;
                const int xx = l15 + kx;
                const bool inb = ((unsigned)yy < 16u) && ((unsigned)xx < 16u);
                const int pix = inb ? (yy * 16 + xx) : 0;
                uint4 av = ldsZ[pix * 8 + (g ^ (pix & 7))];
                if (!inb) { av.x = 0u; av.y = 0u; av.z = 0u; av.w = 0u; }
                bf16x8 afrag = __builtin_bit_cast(bf16x8, av);
#pragma unroll
                for (int oct = 0; oct < 4; ++oct)
                    acc[r][oct] = __builtin_amdgcn_mfma_f32_16x16x32_bf16(
                        afrag, bfrag[oct], acc[r][oct], 0, 0, 0);
            }
        }
    }
}

// ---------------------------------------------------------------------------
// Generic MFMA conv: X bf16 [img][256][64] -> out bf16 [img][256][64]
// ---------------------------------------------------------------------------
struct ConvDesc {
    const uint4* X;
    const uint4* W;
    const float* bias;      // nullptr -> no bias
    unsigned short* out;
    int relu;
};
struct ConvBatch { ConvDesc d[6]; };

__global__ __launch_bounds__(512)
void conv_mfma_k(ConvBatch cb)
{
    __shared__ uint4 ldsZ[2048];
    const ConvDesc d = cb.d[blockIdx.y];
    const int img = blockIdx.x;
    const int tid = threadIdx.x;

    const uint4* Xi = d.X + img * 2048;
#pragma unroll
    for (int i = 0; i < 4; ++i) {
        int u = tid * 4 + i;
        int px = u >> 3, g = u & 7;
        ldsZ[px * 8 + (g ^ (px & 7))] = Xi[u];
    }
    __syncthreads();

    const int lane = tid & 63, wv = tid >> 6;
    const int l15 = lane & 15, l4 = lane >> 4;
    f32x4 zz = {0.f, 0.f, 0.f, 0.f};
    f32x4 acc[2][4];
#pragma unroll
    for (int r = 0; r < 2; ++r)
#pragma unroll
        for (int o = 0; o < 4; ++o) acc[r][o] = zz;

    conv_tiles2(ldsZ, d.W, wv * 2, lane, acc);

#pragma unroll
    for (int oct = 0; oct < 4; ++oct) {
        const int oc = oct * 16 + l15;
        const float b = d.bias ? d.bias[oc] : 0.f;
#pragma unroll
        for (int r = 0; r < 2; ++r)
#pragma unroll
            for (int e = 0; e < 4; ++e) {
                float v = acc[r][oct][e] + b;
                if (d.relu) v = fmaxf(v, 0.f);
                const int px = (wv * 2 + r) * 16 + l4 * 4 + e;
                d.out[(img * PXI + px) * CH + oc] = f2bf(v);
            }
    }
}

// ---------------------------------------------------------------------------
// Pair kernel: block bi -> output node imgb = bi/10, a-group = bi%10 (2 a's).
// Per pair: z = relu(A[b]+B[a]) in LDS -> msg conv; zg -> gate conv;
// accout += msg * sigmoid(gate). One atomic pass at the end.
// ---------------------------------------------------------------------------
static __device__ __forceinline__ unsigned radd2(unsigned a, unsigned b) {
    float a0 = __builtin_bit_cast(float, a << 16);
    float a1 = __builtin_bit_cast(float, a & 0xffff0000u);
    float b0 = __builtin_bit_cast(float, b << 16);
    float b1 = __builtin_bit_cast(float, b & 0xffff0000u);
    float s0 = fmaxf(a0 + b0, 0.f);
    float s1 = fmaxf(a1 + b1, 0.f);
    return (unsigned)f2bf(s0) | ((unsigned)f2bf(s1) << 16);
}

static __device__ __forceinline__ void build_z(uint4* ldsZ, const uint4* __restrict__ A,
                                               const uint4* __restrict__ B, int tid)
{
#pragma unroll
    for (int i = 0; i < 4; ++i) {
        int u = tid * 4 + i;
        uint4 a = A[u], b = B[u];
        uint4 o;
        o.x = radd2(a.x, b.x);
        o.y = radd2(a.y, b.y);
        o.z = radd2(a.z, b.z);
        o.w = radd2(a.w, b.w);
        int px = u >> 3, g = u & 7;
        ldsZ[px * 8 + (g ^ (px & 7))] = o;
    }
}

__global__ __launch_bounds__(512)
void pair_mfma_k(const uint4* __restrict__ Abf, const uint4* __restrict__ Bbf,
                 const uint4* __restrict__ Agbf, const uint4* __restrict__ Bgbf,
                 const uint4* __restrict__ W2, const uint4* __restrict__ Wg2,
                 const float* __restrict__ b2, const float* __restrict__ bg2,
                 float* __restrict__ accum)
{
    __shared__ uint4 ldsZ[2048];
    const int bi   = blockIdx.x;          // 0..399
    const int imgb = bi / 10;
    const int agrp = bi % 10;
    const int n    = imgb / 20;
    const int tid  = threadIdx.x;
    const int lane = tid & 63, wv = tid >> 6;
    const int l15 = lane & 15, l4 = lane >> 4;

    f32x4 zz = {0.f, 0.f, 0.f, 0.f};
    f32x4 accout[2][4];
#pragma unroll
    for (int r = 0; r < 2; ++r)
#pragma unroll
        for (int o = 0; o < 4; ++o) accout[r][o] = zz;

    for (int ia = 0; ia < 2; ++ia) {
        const int imga = n * 20 + agrp * 2 + ia;

        build_z(ldsZ, Abf + imgb * 2048, Bbf + imga * 2048, tid);
        __syncthreads();
        f32x4 accm[2][4];
#pragma unroll
        for (int r = 0; r < 2; ++r)
#pragma unroll
            for (int o = 0; o < 4; ++o) accm[r][o] = zz;
        conv_tiles2(ldsZ, W2, wv * 2, lane, accm);
        __syncthreads();

        build_z(ldsZ, Agbf + imgb * 2048, Bgbf + imga * 2048, tid);
        __syncthreads();
        f32x4 accg[2][4];
#pragma unroll
        for (int r = 0; r < 2; ++r)
#pragma unroll
            for (int o = 0; o < 4; ++o) accg[r][o] = zz;
        conv_tiles2(ldsZ, Wg2, wv * 2, lane, accg);
        __syncthreads();

#pragma unroll
        for (int oct = 0; oct < 4; ++oct) {
            const float bm = b2[oct * 16 + l15];
            const float bg = bg2[oct * 16 + l15];
#pragma unroll
            for (int r = 0; r < 2; ++r)
#pragma unroll
                for (int e = 0; e < 4; ++e) {
                    float m  = accm[r][oct][e] + bm;
                    float gt = accg[r][oct][e] + bg;
                    accout[r][oct][e] += m * (1.f / (1.f + __expf(-gt)));
                }
        }
    }

#pragma unroll
    for (int oct = 0; oct < 4; ++oct)
#pragma unroll
        for (int r = 0; r < 2; ++r)
#pragma unroll
            for (int e = 0; e < 4; ++e) {
                const int px = (wv * 2 + r) * 16 + l4 * 4 + e;
                atomicAdd(&accum[(imgb * PXI + px) * CH + oct * 16 + l15],
                          accout[r][oct][e]);
            }
}

// ---------------------------------------------------------------------------
// Weight repack: src fp32 [oc][CIN_src][3][3] -> dst bf16 [kk][64 oc][64 ci]
// ---------------------------------------------------------------------------
struct WPrep { const float* src; unsigned short* dst; int cin_src; int cioff; int nvalid; };
struct WPrepBatch { WPrep w[11]; };

__global__ __launch_bounds__(256)
void prep_w_k(WPrepBatch wb)
{
    const WPrep p = wb.w[blockIdx.x];
    const int idx = blockIdx.y * 256 + threadIdx.x;   // 0..36863
    const int kk = idx >> 12;
    const int oc = (idx >> 6) & 63;
    const int ci = idx & 63;
    float v = 0.f;
    if (ci < p.nvalid)
        v = p.src[(oc * p.cin_src + p.cioff + ci) * 9 + kk];
    p.dst[idx] = f2bf(v);
}

// Xpad: [img][px][64] bf16, ch0 = t, ch1..32 = x, rest 0
__global__ __launch_bounds__(256)
void prep_x_k(const float* __restrict__ x, const float* __restrict__ t,
              unsigned short* __restrict__ Xpad)
{
    const int idx = blockIdx.x * 256 + threadIdx.x;   // 0..655359
    const int img = idx >> 14;
    const int px  = (idx >> 6) & 255;
    const int ch  = idx & 63;
    float v;
    if (ch == 0)      v = t[0];
    else if (ch <= 32) v = x[((img * 32) + (ch - 1)) * PXI + px];
    else               v = 0.f;
    Xpad[idx] = f2bf(v);
}

// out fp32 [img][oc][px] = u * sigmoid(ug) + accum/19   (u/ug/accum are px-major)
__global__ __launch_bounds__(256)
void final_k(const unsigned short* __restrict__ u_lin,
             const unsigned short* __restrict__ ug_lin,
             const float* __restrict__ accum, float* __restrict__ out)
{
    const int idx = blockIdx.x * 256 + threadIdx.x;   // 0..655359
    const int img = idx >> 14;
    const int oc  = (idx >> 8) & 63;
    const int px  = idx & 255;
    const int j = (img * PXI + px) * CH + oc;
    float u = bfu2f(u_lin[j]);
    float g = bfu2f(ug_lin[j]);
    out[idx] = u * (1.f / (1.f + __expf(-g))) + accum[j] * (1.f / 19.f);
}

// ---------------------------------------------------------------------------
extern "C" void kernel_launch(void* const* d_in, const int* in_sizes, int n_in,
                              void* d_out, int out_size, void* d_ws, size_t ws_size,
                              hipStream_t stream)
{
    const float* t     = (const float*)d_in[0];
    const float* x     = (const float*)d_in[1];
    const float* w_map = (const float*)d_in[2];
    const float* b_map = (const float*)d_in[3];
    const float* w_u1  = (const float*)d_in[4];
    const float* b_u1  = (const float*)d_in[5];
    const float* w_u2  = (const float*)d_in[6];
    const float* b_u2  = (const float*)d_in[7];
    const float* w_ug1 = (const float*)d_in[8];
    const float* b_ug1 = (const float*)d_in[9];
    const float* w_ug2 = (const float*)d_in[10];
    const float* b_ug2 = (const float*)d_in[11];
    const float* w_b1  = (const float*)d_in[12];
    const float* b_b1  = (const float*)d_in[13];
    const float* w_b2  = (const float*)d_in[14];
    const float* b_b2  = (const float*)d_in[15];
    const float* w_bg1 = (const float*)d_in[16];
    const float* b_bg1 = (const float*)d_in[17];
    const float* w_bg2 = (const float*)d_in[18];
    const float* b_bg2 = (const float*)d_in[19];

    float* out = (float*)d_out;
    char* ws = (char*)d_ws;

    const size_t ABYTES = (size_t)SB_ELEM * 2;      // 1,310,720 B per bf16 tensor
    unsigned short* Xpad   = (unsigned short*)(ws + 0 * ABYTES);
    unsigned short* h      = (unsigned short*)(ws + 1 * ABYTES);
    unsigned short* p1     = (unsigned short*)(ws + 2 * ABYTES);
    unsigned short* pg1    = (unsigned short*)(ws + 3 * ABYTES);
    unsigned short* u_lin  = (unsigned short*)(ws + 4 * ABYTES);
    unsigned short* ug_lin = (unsigned short*)(ws + 5 * ABYTES);
    unsigned short* Abuf   = (unsigned short*)(ws + 6 * ABYTES);
    unsigned short* Bbuf   = (unsigned short*)(ws + 7 * ABYTES);
    unsigned short* Agbuf  = (unsigned short*)(ws + 8 * ABYTES);
    unsigned short* Bgbuf  = (unsigned short*)(ws + 9 * ABYTES);
    float* accum = (float*)(ws + 10 * ABYTES);      // 2,621,440 B
    char* wbase = ws + 10 * ABYTES + (size_t)SB_ELEM * 4;
    const size_t WBYTES = 9 * 64 * 64 * 2;          // 73,728 B per weight tensor
    unsigned short* Wmap  = (unsigned short*)(wbase + 0 * WBYTES);
    unsigned short* Wu1   = (unsigned short*)(wbase + 1 * WBYTES);
    unsigned short* Wu2   = (unsigned short*)(wbase + 2 * WBYTES);
    unsigned short* Wug1  = (unsigned short*)(wbase + 3 * WBYTES);
    unsigned short* Wug2  = (unsigned short*)(wbase + 4 * WBYTES);
    unsigned short* Wb1a  = (unsigned short*)(wbase + 5 * WBYTES);
    unsigned short* Wb1b  = (unsigned short*)(wbase + 6 * WBYTES);
    unsigned short* Wbg1a = (unsigned short*)(wbase + 7 * WBYTES);
    unsigned short* Wbg1b = (unsigned short*)(wbase + 8 * WBYTES);
    unsigned short* Wb2   = (unsigned short*)(wbase + 9 * WBYTES);
    unsigned short* Wbg2  = (unsigned short*)(wbase + 10 * WBYTES);

    hipMemsetAsync(accum, 0, (size_t)SB_ELEM * 4, stream);

    // --- weight repack ---
    WPrepBatch wb;
    wb.w[0]  = { w_map, Wmap,  33,  0, 33 };
    wb.w[1]  = { w_u1,  Wu1,   64,  0, 64 };
    wb.w[2]  = { w_u2,  Wu2,   64,  0, 64 };
    wb.w[3]  = { w_ug1, Wug1,  64,  0, 64 };
    wb.w[4]  = { w_ug2, Wug2,  64,  0, 64 };
    wb.w[5]  = { w_b1,  Wb1a, 128,  0, 64 };
    wb.w[6]  = { w_b1,  Wb1b, 128, 64, 64 };
    wb.w[7]  = { w_bg1, Wbg1a,128,  0, 64 };
    wb.w[8]  = { w_bg1, Wbg1b,128, 64, 64 };
    wb.w[9]  = { w_b2,  Wb2,   64,  0, 64 };
    wb.w[10] = { w_bg2, Wbg2,  64,  0, 64 };
    prep_w_k<<<dim3(11, 144), dim3(256), 0, stream>>>(wb);

    prep_x_k<<<dim3(SB_ELEM / 256), dim3(256), 0, stream>>>(x, t, Xpad);

    // --- map conv: h = conv(Xpad, w_map) + b_map ---
    ConvBatch cm{};
    cm.d[0] = { (const uint4*)Xpad, (const uint4*)Wmap, b_map, h, 0 };
    for (int i = 1; i < 6; ++i) cm.d[i] = cm.d[0];
    conv_mfma_k<<<dim3(NIMG, 1), dim3(512), 0, stream>>>(cm);

    // --- stage 1: six convs from h ---
    ConvBatch c1{};
    c1.d[0] = { (const uint4*)h, (const uint4*)Wu1,   b_u1,  p1,    1 };
    c1.d[1] = { (const uint4*)h, (const uint4*)Wug1,  b_ug1, pg1,   1 };
    c1.d[2] = { (const uint4*)h, (const uint4*)Wb1a,  b_b1,  Abuf,  0 };
    c1.d[3] = { (const uint4*)h, (const uint4*)Wb1b,  nullptr, Bbuf, 0 };
    c1.d[4] = { (const uint4*)h, (const uint4*)Wbg1a, b_bg1, Agbuf, 0 };
    c1.d[5] = { (const uint4*)h, (const uint4*)Wbg1b, nullptr, Bgbuf, 0 };
    conv_mfma_k<<<dim3(NIMG, 6), dim3(512), 0, stream>>>(c1);

    // --- stage 2: u_lin, ug_lin ---
    ConvBatch c2{};
    c2.d[0] = { (const uint4*)p1,  (const uint4*)Wu2,  b_u2,  u_lin,  0 };
    c2.d[1] = { (const uint4*)pg1, (const uint4*)Wug2, b_ug2, ug_lin, 0 };
    for (int i = 2; i < 6; ++i) c2.d[i] = c2.d[0];
    conv_mfma_k<<<dim3(NIMG, 2), dim3(512), 0, stream>>>(c2);

    // --- pairwise messages ---
    pair_mfma_k<<<dim3(400), dim3(512), 0, stream>>>(
        (const uint4*)Abuf, (const uint4*)Bbuf, (const uint4*)Agbuf, (const uint4*)Bgbuf,
        (const uint4*)Wb2, (const uint4*)Wbg2, b_b2, b_bg2, accum);

    // --- final combine (transpose to [img][oc][px]) ---
    final_k<<<dim3(SB_ELEM / 256), dim3(256), 0, stream>>>(u_lin, ug_lin, accum, out);
}